// Round 3
// baseline (233.027 us; speedup 1.0000x reference)
//
#include <hip/hip_runtime.h>

// LocalCausalAttention: b=4, t=4096, h=16, d=64, window W=64.
// R6: swapped-QK^T single-barrier design. WG = 128 threads = 2 waves = one
// t-block; wave wv owns q-rows [T0+32wv, +32) and its 96-key window.
//   S^T = K*Q^T via mfma_32x32x16 (A=K, B=Q^T): both frags are 8 contiguous
//   floats/lane -> Q,K global->register, NO LDS, no staging barrier.
//   C col = lane&31 = q  ->  softmax fully in-lane (tree + 2 shfl_xor(32)).
//   P stays in registers: sigma-permuted key order makes S^T acc regs the
//   PV A-fragment directly (slot 8*hl+j == reg 8*(s&1)+j, verified).
//   Only V goes through LDS (16KB sigma-permuted, XOR-swizzled V^T);
//   ONE __syncthreads total. rden+q-mask folded into P before bf16 pack.
// Out C-frag: col=d -> coalesced 128B stores.

#define TT 4096
#define HH 16
#define DD 64
#define WW 64
#define NBLK (TT / WW)

typedef __attribute__((ext_vector_type(8))) short bf16x8;
typedef __attribute__((ext_vector_type(16))) float f32x16;

// f32->bf16 RNE without NaN guard (inputs are finite gaussians / zeros)
static __device__ __forceinline__ uint bfr(float x) {
    uint u = __builtin_bit_cast(uint, x);
    return (u + 0x7FFFu + ((u >> 16) & 1u)) >> 16;
}
static __device__ __forceinline__ ushort f2bf(float x) { return (ushort)bfr(x); }
static __device__ __forceinline__ uint pack2(float a, float b) {
    return bfr(a) | (bfr(b) << 16);
}
// V^T row swizzle: unit16B ^= vsw(d); spans all 16 units over any 16 consecutive d
static __device__ __forceinline__ int vsw(int d) { return ((d >> 2) ^ d) & 15; }

__global__ __launch_bounds__(128, 3)
void lca_fwd(const float* __restrict__ q, const float* __restrict__ k,
             const float* __restrict__ v, const int* __restrict__ am,
             float* __restrict__ out)
{
    // XCD-aware bijective swizzle (64 % 8 == 0)
    const int jb = ((blockIdx.x & 7) << 3) | (blockIdx.x >> 3);
    const int hd = blockIdx.y;
    const int bi = blockIdx.z;

    __shared__ __align__(16) ushort sVt[8192];   // V^T sigma-permuted, 16KB

    const int tid  = threadIdx.x;        // 0..127
    const int wv   = tid >> 6;
    const int lane = tid & 63;
    const int l31  = lane & 31, hl = lane >> 5;

    const int T0 = jb * WW;
    const int Tq = T0 + 32 * wv;         // wave's q start; window keys [Tq-64, Tq+32)
    const size_t rowstride = (size_t)HH * DD;
    const size_t hoff = ((size_t)bi * TT) * rowstride + (size_t)hd * DD;
    const int* amb = am + (size_t)bi * TT;

    // ---- validity ballots (no LDS) ----
    long tok0 = (long)Tq - 64 + lane;
    unsigned long long m_lo = __ballot((tok0 >= 0) && (amb[tok0 < 0 ? 0 : tok0] != 0));
    unsigned int m_hi = (unsigned int)__ballot(amb[Tq + l31] != 0);

    // ---- V^T staging: both waves stage shared 128-key window [T0-64, T0+64) ----
    // pos = sigma(key): swap bits 2<->3 within each 16 -> PV B-frag reads are b128.
    {
        const int d0 = (tid & 15) * 4;
        const int rb = tid >> 4;
        #pragma unroll
        for (int p = 0; p < 16; ++p) {
            int kl = p * 8 + rb;                       // 0..127
            long tok = (long)T0 - 64 + kl;
            if (tok < 0) tok = 0;                      // masked via m_lo -> P=0
            const float4 x = *(const float4*)(v + hoff + (size_t)tok * rowstride + d0);
            int e = kl & 15;
            int pos = (kl & ~15) | (e & 3) | ((e & 8) >> 1) | ((e & 4) << 1);
            int pu = pos >> 3, p7 = pos & 7;
            sVt[(d0 + 0) * 128 + ((pu ^ vsw(d0 + 0)) << 3) + p7] = f2bf(x.x);
            sVt[(d0 + 1) * 128 + ((pu ^ vsw(d0 + 1)) << 3) + p7] = f2bf(x.y);
            sVt[(d0 + 2) * 128 + ((pu ^ vsw(d0 + 2)) << 3) + p7] = f2bf(x.z);
            sVt[(d0 + 3) * 128 + ((pu ^ vsw(d0 + 3)) << 3) + p7] = f2bf(x.w);
        }
    }

    // ---- Q B-fragments: lane = col q = l31, k-rows d = 16*ds + 8*hl + 0..7 ----
    bf16x8 Bq[4];
    {
        const float* qr = q + hoff + (size_t)(Tq + l31) * rowstride + hl * 8;
        #pragma unroll
        for (int ds = 0; ds < 4; ++ds) {
            float4 a = *(const float4*)(qr + ds * 16);
            float4 b = *(const float4*)(qr + ds * 16 + 4);
            union { bf16x8 v8; uint u[4]; } w;
            w.u[0] = pack2(a.x, a.y); w.u[1] = pack2(a.z, a.w);
            w.u[2] = pack2(b.x, b.y); w.u[3] = pack2(b.z, b.w);
            Bq[ds] = w.v8;
        }
    }

    // ---- S^T = K*Q^T: 3 key-tiles x 4 d-steps; K straight from global ----
    float s[48];
    #pragma unroll
    for (int t = 0; t < 3; ++t) {
        long krw = (long)Tq - 64 + 32 * t + l31;
        if (krw < 0) krw = 0;                          // masked later
        const float* kr = k + hoff + (size_t)krw * rowstride + hl * 8;
        f32x16 a;
        #pragma unroll
        for (int i = 0; i < 16; ++i) a[i] = 0.f;
        #pragma unroll
        for (int ds = 0; ds < 4; ++ds) {
            float4 xx = *(const float4*)(kr + ds * 16);
            float4 yy = *(const float4*)(kr + ds * 16 + 4);
            union { bf16x8 v8; uint u[4]; } w;
            w.u[0] = pack2(xx.x, xx.y); w.u[1] = pack2(xx.z, xx.w);
            w.u[2] = pack2(yy.x, yy.y); w.u[3] = pack2(yy.z, yy.w);
            a = __builtin_amdgcn_mfma_f32_32x32x16_bf16(w.v8, Bq[ds], a, 0, 0, 0);
        }
        #pragma unroll
        for (int r = 0; r < 16; ++r) s[t * 16 + r] = a[r];
    }

    // ---- in-register masked softmax (lane owns q = l31) ----
    const int ql = l31;
    // band: valid iff ql+1 <= kl <= ql+64; tile1 (kl 32..63) is always in-band.
    float vb[48];
    #pragma unroll
    for (int t = 0; t < 3; ++t)
        #pragma unroll
        for (int r = 0; r < 16; ++r) {
            int kl = 32 * t + (r & 3) + 8 * (r >> 2) + 4 * hl;
            bool band = (t == 0) ? (kl > ql) : (t == 2 ? (kl - 64 <= ql) : true);
            vb[t * 16 + r] = band ? 1.f : 0.f;
        }
    if (!((m_lo == ~0ull) && (m_hi == 0xFFFFFFFFu))) {   // wave-uniform slow path
        #pragma unroll
        for (int t = 0; t < 3; ++t)
            #pragma unroll
            for (int r = 0; r < 16; ++r) {
                int kl = 32 * t + (r & 3) + 8 * (r >> 2) + 4 * hl;
                uint bit = (kl < 64) ? (uint)((m_lo >> kl) & 1ull)
                                     : ((m_hi >> (kl - 64)) & 1u);
                vb[t * 16 + r] *= (float)bit;
            }
    }
    // max over raw scores (shift-invariant; all values finite), tree + 1 shfl
    float mx[24];
    #pragma unroll
    for (int i = 0; i < 24; ++i) mx[i] = fmaxf(s[i], s[i + 24]);
    #pragma unroll
    for (int i = 0; i < 12; ++i) mx[i] = fmaxf(mx[i], mx[i + 12]);
    #pragma unroll
    for (int i = 0; i < 6;  ++i) mx[i] = fmaxf(mx[i], mx[i + 6]);
    float rmax = fmaxf(fmaxf(fmaxf(mx[0], mx[1]), fmaxf(mx[2], mx[3])),
                       fmaxf(mx[4], mx[5]));
    rmax = fmaxf(rmax, __shfl_xor(rmax, 32, 64));

    const float CEXP = 0.125f * 1.44269504088896f;   // scale * log2(e)
    float p[48];
    #pragma unroll
    for (int i = 0; i < 48; ++i)
        p[i] = exp2f((s[i] - rmax) * CEXP) * vb[i];

    float t24[24];
    #pragma unroll
    for (int i = 0; i < 24; ++i) t24[i] = p[i] + p[i + 24];
    #pragma unroll
    for (int i = 0; i < 12; ++i) t24[i] += t24[i + 12];
    #pragma unroll
    for (int i = 0; i < 6;  ++i) t24[i] += t24[i + 6];
    float sum = ((t24[0] + t24[1]) + (t24[2] + t24[3])) + (t24[4] + t24[5]);
    sum += __shfl_xor(sum, 32, 64);

    float rden = (sum > 0.f ? 1.f / sum : 0.f) * (float)((m_hi >> ql) & 1u);
    #pragma unroll
    for (int i = 0; i < 48; ++i) p[i] *= rden;       // fold denom + q-mask into P

    __syncthreads();   // the ONLY barrier: V^T writes visible to both waves

    // ---- OUT = P*V: A = packed P regs (sigma order), B = sVt b128 reads ----
    f32x16 O0, O1;
    #pragma unroll
    for (int i = 0; i < 16; ++i) { O0[i] = 0.f; O1[i] = 0.f; }
    #pragma unroll
    for (int st = 0; st < 6; ++st) {
        union { bf16x8 v8; uint u[4]; } A;
        const int pb = 16 * (st >> 1) + 8 * (st & 1);
        #pragma unroll
        for (int j = 0; j < 4; ++j)
            A.u[j] = pack2(p[pb + 2 * j], p[pb + 2 * j + 1]);
        const int Ub = 4 * wv + 2 * st + hl;         // position-group unit base
        {
            int d = l31;
            const bf16x8 B0 = *(const bf16x8*)(&sVt[d * 128 + ((Ub ^ vsw(d)) << 3)]);
            O0 = __builtin_amdgcn_mfma_f32_32x32x16_bf16(A.v8, B0, O0, 0, 0, 0);
        }
        {
            int d = 32 + l31;
            const bf16x8 B1 = *(const bf16x8*)(&sVt[d * 128 + ((Ub ^ vsw(d)) << 3)]);
            O1 = __builtin_amdgcn_mfma_f32_32x32x16_bf16(A.v8, B1, O1, 0, 0, 0);
        }
    }

    // ---- stores: C col = d -> lanes 0..31 contiguous 128B per row ----
    float* ob = out + hoff + (size_t)Tq * rowstride;
    #pragma unroll
    for (int r = 0; r < 16; ++r) {
        int qrow = (r & 3) + 8 * (r >> 2) + 4 * hl;
        float* orow = ob + (size_t)qrow * rowstride;
        orow[l31]      = O0[r];
        orow[32 + l31] = O1[r];
    }
}

extern "C" void kernel_launch(void* const* d_in, const int* in_sizes, int n_in,
                              void* d_out, int out_size, void* d_ws, size_t ws_size,
                              hipStream_t stream) {
    const float* q  = (const float*)d_in[0];
    const float* k  = (const float*)d_in[1];
    const float* v  = (const float*)d_in[2];
    const int*   am = (const int*)d_in[3];
    float* outp = (float*)d_out;

    const int b = in_sizes[3] / TT;   // 4
    dim3 grid(NBLK, HH, b);
    dim3 block(128);
    lca_fwd<<<grid, block, 0, stream>>>(q, k, v, am, outp);
}

// Round 4
// 229.617 us; speedup vs baseline: 1.0149x; 1.0149x over previous
//
#include <hip/hip_runtime.h>

// LocalCausalAttention: b=4, t=4096, h=16, d=64, window W=64.
// R7: R6 structure (swapped-QK^T, lane-local softmax, single barrier) with
// MAX MEMORY-LEVEL PARALLELISM: __launch_bounds__(128,2) lifts the VGPR cap
// to 256 so all 48 input float4 loads sit in independent registers, issued
// as one burst before any consumption (R4/R6 had VGPR 48/60 -> compiler
// serialized loads behind converts -> ~6-10 lines in flight -> 2 TB/s
// latency ceiling). Consume order: Q frags -> QK^T -> softmax (V still in
// flight) -> V cvt+LDS -> barrier -> PV. P packed to bf16 pairs with rden
// folded right after softmax (24 uints live across barrier, no PV repack).

#define TT 4096
#define HH 16
#define DD 64
#define WW 64
#define NBLK (TT / WW)

typedef __attribute__((ext_vector_type(8))) short bf16x8;
typedef __attribute__((ext_vector_type(16))) float f32x16;

// f32->bf16 RNE without NaN guard (inputs are finite gaussians / zeros)
static __device__ __forceinline__ uint bfr(float x) {
    uint u = __builtin_bit_cast(uint, x);
    return (u + 0x7FFFu + ((u >> 16) & 1u)) >> 16;
}
static __device__ __forceinline__ ushort f2bf(float x) { return (ushort)bfr(x); }
static __device__ __forceinline__ uint pack2(float a, float b) {
    return bfr(a) | (bfr(b) << 16);
}
// V^T row swizzle: unit16B ^= vsw(d); spans all 16 units over any 16 consecutive d
static __device__ __forceinline__ int vsw(int d) { return ((d >> 2) ^ d) & 15; }

__global__ __launch_bounds__(128, 2)
void lca_fwd(const float* __restrict__ q, const float* __restrict__ k,
             const float* __restrict__ v, const int* __restrict__ am,
             float* __restrict__ out)
{
    // XCD-aware bijective swizzle (64 % 8 == 0)
    const int jb = ((blockIdx.x & 7) << 3) | (blockIdx.x >> 3);
    const int hd = blockIdx.y;
    const int bi = blockIdx.z;

    __shared__ __align__(16) ushort sVt[8192];   // V^T sigma-permuted, 16KB

    const int tid  = threadIdx.x;        // 0..127
    const int wv   = tid >> 6;
    const int lane = tid & 63;
    const int l31  = lane & 31, hl = lane >> 5;

    const int T0 = jb * WW;
    const int Tq = T0 + 32 * wv;         // wave's q start; window keys [Tq-64, Tq+32)
    const size_t rowstride = (size_t)HH * DD;
    const size_t hoff = ((size_t)bi * TT) * rowstride + (size_t)hd * DD;
    const int* amb = am + (size_t)bi * TT;

    // ---- mask loads FIRST (oldest in vmcnt queue -> ballots drain cheap) ----
    long tok0 = (long)Tq - 64 + lane;
    int am_lo = amb[tok0 < 0 ? 0 : tok0];
    int am_hi = amb[Tq + l31];

    // ---- issue ALL input loads as one burst into independent registers ----
    float4 vq[8], vk[24], vv[16];
    {
        const float* qr = q + hoff + (size_t)(Tq + l31) * rowstride + hl * 8;
        #pragma unroll
        for (int ds = 0; ds < 4; ++ds) {
            vq[2 * ds]     = *(const float4*)(qr + ds * 16);
            vq[2 * ds + 1] = *(const float4*)(qr + ds * 16 + 4);
        }
    }
    #pragma unroll
    for (int t = 0; t < 3; ++t) {
        long krw = (long)Tq - 64 + 32 * t + l31;
        const float* kr = k + hoff + (size_t)(krw < 0 ? 0 : krw) * rowstride + hl * 8;
        #pragma unroll
        for (int ds = 0; ds < 4; ++ds) {
            vk[8 * t + 2 * ds]     = *(const float4*)(kr + ds * 16);
            vk[8 * t + 2 * ds + 1] = *(const float4*)(kr + ds * 16 + 4);
        }
    }
    const int d0 = (tid & 15) * 4;
    const int rb = tid >> 4;
    #pragma unroll
    for (int p = 0; p < 16; ++p) {
        int kl = p * 8 + rb;                       // 0..127
        long tok = (long)T0 - 64 + kl;
        if (tok < 0) tok = 0;                      // masked via m_lo -> P=0
        vv[p] = *(const float4*)(v + hoff + (size_t)tok * rowstride + d0);
    }

    // ---- validity ballots ----
    unsigned long long m_lo = __ballot((tok0 >= 0) && (am_lo != 0));
    unsigned int m_hi = (unsigned int)__ballot(am_hi != 0);
    const bool fastmask = (m_lo == ~0ull) && (m_hi == 0xFFFFFFFFu);

    // ---- Q B-fragments: lane = col q = l31, k-rows d = 16*ds + 8*hl + 0..7 ----
    bf16x8 Bq[4];
    #pragma unroll
    for (int ds = 0; ds < 4; ++ds) {
        union { bf16x8 v8; uint u[4]; } w;
        w.u[0] = pack2(vq[2 * ds].x,     vq[2 * ds].y);
        w.u[1] = pack2(vq[2 * ds].z,     vq[2 * ds].w);
        w.u[2] = pack2(vq[2 * ds + 1].x, vq[2 * ds + 1].y);
        w.u[3] = pack2(vq[2 * ds + 1].z, vq[2 * ds + 1].w);
        Bq[ds] = w.v8;
    }

    // ---- S^T = K*Q^T: 3 key-tiles x 4 d-steps ----
    float s[48];
    #pragma unroll
    for (int t = 0; t < 3; ++t) {
        f32x16 a;
        #pragma unroll
        for (int i = 0; i < 16; ++i) a[i] = 0.f;
        #pragma unroll
        for (int ds = 0; ds < 4; ++ds) {
            union { bf16x8 v8; uint u[4]; } w;
            w.u[0] = pack2(vk[8 * t + 2 * ds].x,     vk[8 * t + 2 * ds].y);
            w.u[1] = pack2(vk[8 * t + 2 * ds].z,     vk[8 * t + 2 * ds].w);
            w.u[2] = pack2(vk[8 * t + 2 * ds + 1].x, vk[8 * t + 2 * ds + 1].y);
            w.u[3] = pack2(vk[8 * t + 2 * ds + 1].z, vk[8 * t + 2 * ds + 1].w);
            a = __builtin_amdgcn_mfma_f32_32x32x16_bf16(w.v8, Bq[ds], a, 0, 0, 0);
        }
        #pragma unroll
        for (int r = 0; r < 16; ++r) s[t * 16 + r] = a[r];
    }

    // ---- in-register masked softmax (lane owns q = l31); V loads still in flight ----
    const int ql = l31;
    // max over raw scores (shift-invariant; all values finite), tree + 1 shfl.
    // Out-of-band slots may inflate rmax; harmless (softmax shift-invariance).
    float mx[24];
    #pragma unroll
    for (int i = 0; i < 24; ++i) mx[i] = fmaxf(s[i], s[i + 24]);
    #pragma unroll
    for (int i = 0; i < 12; ++i) mx[i] = fmaxf(mx[i], mx[i + 12]);
    #pragma unroll
    for (int i = 0; i < 6;  ++i) mx[i] = fmaxf(mx[i], mx[i + 6]);
    float rmax = fmaxf(fmaxf(fmaxf(mx[0], mx[1]), fmaxf(mx[2], mx[3])),
                       fmaxf(mx[4], mx[5]));
    rmax = fmaxf(rmax, __shfl_xor(rmax, 32, 64));

    const float CEXP = 0.125f * 1.44269504088896f;   // scale * log2(e)
    float p[48];
    #pragma unroll
    for (int t = 0; t < 3; ++t)
        #pragma unroll
        for (int r = 0; r < 16; ++r) {
            int i  = t * 16 + r;
            int kl = 32 * t + (r & 3) + 8 * (r >> 2) + 4 * hl;
            float pe = exp2f((s[i] - rmax) * CEXP);
            bool band = (t == 0) ? (kl > ql) : (t == 2 ? (kl - 64 <= ql) : true);
            pe = band ? pe : 0.f;
            if (!fastmask) {                         // wave-uniform slow path
                uint bit = (kl < 64) ? (uint)((m_lo >> kl) & 1ull)
                                     : ((m_hi >> (kl - 64)) & 1u);
                pe *= (float)bit;
            }
            p[i] = pe;
        }

    float t24[24];
    #pragma unroll
    for (int i = 0; i < 24; ++i) t24[i] = p[i] + p[i + 24];
    #pragma unroll
    for (int i = 0; i < 12; ++i) t24[i] += t24[i + 12];
    #pragma unroll
    for (int i = 0; i < 6;  ++i) t24[i] += t24[i + 6];
    float sum = ((t24[0] + t24[1]) + (t24[2] + t24[3])) + (t24[4] + t24[5]);
    sum += __shfl_xor(sum, 32, 64);

    float rden = (sum > 0.f ? 1.f / sum : 0.f) * (float)((m_hi >> ql) & 1u);

    // pack P to bf16 pairs with rden folded: 24 uints live across the barrier
    uint pk[24];
    #pragma unroll
    for (int m = 0; m < 24; ++m)
        pk[m] = pack2(p[2 * m] * rden, p[2 * m + 1] * rden);

    // ---- V^T staging (loads long in flight by now): sigma-permuted, swizzled ----
    #pragma unroll
    for (int pp = 0; pp < 16; ++pp) {
        int kl = pp * 8 + rb;                      // 0..127
        const float4 x = vv[pp];
        int e = kl & 15;
        int pos = (kl & ~15) | (e & 3) | ((e & 8) >> 1) | ((e & 4) << 1);
        int pu = pos >> 3, p7 = pos & 7;
        sVt[(d0 + 0) * 128 + ((pu ^ vsw(d0 + 0)) << 3) + p7] = f2bf(x.x);
        sVt[(d0 + 1) * 128 + ((pu ^ vsw(d0 + 1)) << 3) + p7] = f2bf(x.y);
        sVt[(d0 + 2) * 128 + ((pu ^ vsw(d0 + 2)) << 3) + p7] = f2bf(x.z);
        sVt[(d0 + 3) * 128 + ((pu ^ vsw(d0 + 3)) << 3) + p7] = f2bf(x.w);
    }

    __syncthreads();   // the ONLY barrier: V^T writes visible to both waves

    // ---- OUT = P*V: A = packed P (sigma order), B = sVt b128 reads ----
    f32x16 O0, O1;
    #pragma unroll
    for (int i = 0; i < 16; ++i) { O0[i] = 0.f; O1[i] = 0.f; }
    #pragma unroll
    for (int st = 0; st < 6; ++st) {
        union { bf16x8 v8; uint u[4]; } A;
        const int mb = 8 * (st >> 1) + 4 * (st & 1);
        #pragma unroll
        for (int j = 0; j < 4; ++j) A.u[j] = pk[mb + j];
        const int Ub = 4 * wv + 2 * st + hl;         // position-group unit base
        {
            int d = l31;
            const bf16x8 B0 = *(const bf16x8*)(&sVt[d * 128 + ((Ub ^ vsw(d)) << 3)]);
            O0 = __builtin_amdgcn_mfma_f32_32x32x16_bf16(A.v8, B0, O0, 0, 0, 0);
        }
        {
            int d = 32 + l31;
            const bf16x8 B1 = *(const bf16x8*)(&sVt[d * 128 + ((Ub ^ vsw(d)) << 3)]);
            O1 = __builtin_amdgcn_mfma_f32_32x32x16_bf16(A.v8, B1, O1, 0, 0, 0);
        }
    }

    // ---- stores: C col = d -> lanes 0..31 contiguous 128B per row ----
    float* ob = out + hoff + (size_t)Tq * rowstride;
    #pragma unroll
    for (int r = 0; r < 16; ++r) {
        int qrow = (r & 3) + 8 * (r >> 2) + 4 * hl;
        float* orow = ob + (size_t)qrow * rowstride;
        orow[l31]      = O0[r];
        orow[32 + l31] = O1[r];
    }
}

extern "C" void kernel_launch(void* const* d_in, const int* in_sizes, int n_in,
                              void* d_out, int out_size, void* d_ws, size_t ws_size,
                              hipStream_t stream) {
    const float* q  = (const float*)d_in[0];
    const float* k  = (const float*)d_in[1];
    const float* v  = (const float*)d_in[2];
    const int*   am = (const int*)d_in[3];
    float* outp = (float*)d_out;

    const int b = in_sizes[3] / TT;   // 4
    dim3 grid(NBLK, HH, b);
    dim3 block(128);
    lca_fwd<<<grid, block, 0, stream>>>(q, k, v, am, outp);
}